// Round 2
// baseline (3604.148 us; speedup 1.0000x reference)
//
#include <hip/hip_runtime.h>
#include <cstdint>
#include <cstddef>

#define NN 4096
#define CC 256
#define EE 131072
#define OUTC 16
#define BN_EPS 1e-5f

// ---------------------------------------------------------------- small kernels

__global__ __launch_bounds__(256) void k_zero(float* __restrict__ p, size_t n) {
    size_t i = (size_t)blockIdx.x * blockDim.x + threadIdx.x;
    size_t stride = (size_t)gridDim.x * blockDim.x;
    for (; i < n; i += stride) p[i] = 0.f;
}

__global__ __launch_bounds__(256) void k_build_adj(const int* __restrict__ ei,
                                                   float* __restrict__ A) {
    int e = blockIdx.x * blockDim.x + threadIdx.x;
    if (e < EE) {
        int s = ei[e];        // source
        int t = ei[EE + e];   // target
        atomicAdd(&A[(size_t)t * NN + s], 1.0f);
    }
}

// per-row: d0 = A[i][i]; e = (d0>0)?0:2; deg = rowsum(A)+e; dis=rsqrt(deg)
__global__ __launch_bounds__(256) void k_degree(const float* __restrict__ A,
                                                float* __restrict__ dis,
                                                float* __restrict__ selfw, int n) {
    int i = blockIdx.x;
    int tid = threadIdx.x;
    const float* row = A + (size_t)i * n;
    float s = 0.f;
    for (int j = tid; j < n; j += 256) s += row[j];
    __shared__ float ss[256];
    ss[tid] = s;
    __syncthreads();
    for (int off = 128; off > 0; off >>= 1) {
        if (tid < off) ss[tid] += ss[tid + off];
        __syncthreads();
    }
    if (tid == 0) {
        float d0 = row[i];
        float e = (d0 > 0.f) ? 0.f : 2.f;
        dis[i] = rsqrtf(ss[0] + e);
        selfw[i] = e;
    }
}

// xw[i][c] *= dis[i]   (xw becomes y = dis ⊙ (x@W))
__global__ __launch_bounds__(256) void k_scale_rows(float* __restrict__ xw,
                                                    const float* __restrict__ dis) {
    int i = blockIdx.x, c = threadIdx.x;
    xw[(size_t)i * CC + c] *= dis[i];
}

// out = [relu]( dis_i * (z + selfw_i * y) + b )    where y = dis ⊙ xw
__global__ __launch_bounds__(256) void k_gcn_epilogue(const float* __restrict__ z,
                                                      const float* __restrict__ y,
                                                      const float* __restrict__ dis,
                                                      const float* __restrict__ selfw,
                                                      const float* __restrict__ bias,
                                                      float* __restrict__ out,
                                                      int do_relu) {
    int i = blockIdx.x, c = threadIdx.x;
    float di = dis[i];
    float v = di * (z[(size_t)i * CC + c] + selfw[i] * y[(size_t)i * CC + c]) + bias[c];
    if (do_relu) v = fmaxf(v, 0.f);
    out[(size_t)i * CC + c] = v;
}

__global__ __launch_bounds__(256) void k_wnorm(const float* __restrict__ w,
                                               float* __restrict__ invn) {
    __shared__ float ss[256];
    int tid = threadIdx.x;
    float v = w[tid];
    ss[tid] = v * v;
    __syncthreads();
    for (int off = 128; off > 0; off >>= 1) {
        if (tid < off) ss[tid] += ss[tid + off];
        __syncthreads();
    }
    if (tid == 0) invn[0] = rsqrtf(ss[0]);
}

// score[i] = tanh(dot(h[i],w) * invnorm)
__global__ __launch_bounds__(256) void k_score(const float* __restrict__ h,
                                               const float* __restrict__ w,
                                               const float* __restrict__ invn,
                                               float* __restrict__ score) {
    int i = blockIdx.x, tid = threadIdx.x;
    __shared__ float ss[256];
    ss[tid] = h[(size_t)i * CC + tid] * w[tid];
    __syncthreads();
    for (int off = 128; off > 0; off >>= 1) {
        if (tid < off) ss[tid] += ss[tid + off];
        __syncthreads();
    }
    if (tid == 0) score[i] = tanhf(ss[0] * invn[0]);
}

// stable descending top-k via rank counting: rank = #{s_j > s_i} + #{s_j==s_i, j<i}
__global__ __launch_bounds__(256) void k_topk(const float* __restrict__ score, int n,
                                              int k, int* __restrict__ perm,
                                              float* __restrict__ vals) {
    extern __shared__ float sc[];
    int tid = threadIdx.x;
    for (int j = tid; j < n; j += 256) sc[j] = score[j];
    __syncthreads();
    int i = blockIdx.x * 256 + tid;
    if (i < n) {
        float s = sc[i];
        int rank = 0;
        for (int j = 0; j < n; ++j) {
            float sj = sc[j];
            rank += (sj > s) || (sj == s && j < i);
        }
        if (rank < k) {
            perm[rank] = i;
            vals[rank] = s;
        }
    }
}

// out[a][c] = h[perm[a]][c] * vals[a]
__global__ __launch_bounds__(256) void k_gate(const float* __restrict__ h,
                                              const int* __restrict__ perm,
                                              const float* __restrict__ vals,
                                              float* __restrict__ out) {
    int a = blockIdx.x, c = threadIdx.x;
    out[(size_t)a * CC + c] = h[(size_t)perm[a] * CC + c] * vals[a];
}

// dst[perm[a]][c] += src[a][c]
__global__ __launch_bounds__(256) void k_scatter_add(float* __restrict__ dst,
                                                     const float* __restrict__ src,
                                                     const int* __restrict__ perm) {
    int a = blockIdx.x, c = threadIdx.x;
    dst[(size_t)perm[a] * CC + c] += src[(size_t)a * CC + c];
}

// batch-norm stats over rows with relu applied first
__global__ __launch_bounds__(256) void k_bn_stats(const float* __restrict__ h,
                                                  float* __restrict__ mean,
                                                  float* __restrict__ var, int n) {
    int c = blockIdx.x, tid = threadIdx.x;
    float s = 0.f, s2 = 0.f;
    for (int r = tid; r < n; r += 256) {
        float v = fmaxf(h[(size_t)r * CC + c], 0.f);
        s += v;
        s2 += v * v;
    }
    __shared__ float ss[256], ss2[256];
    ss[tid] = s;
    ss2[tid] = s2;
    __syncthreads();
    for (int off = 128; off > 0; off >>= 1) {
        if (tid < off) { ss[tid] += ss[tid + off]; ss2[tid] += ss2[tid + off]; }
        __syncthreads();
    }
    if (tid == 0) {
        float m = ss[0] / n;
        mean[c] = m;
        var[c] = ss2[0] / n - m * m;
    }
}

// out[i][o] = sum_c norm(relu(h[i][c])) * W[c][o] + b[o]
__global__ __launch_bounds__(256) void k_bn_linear(const float* __restrict__ h,
                                                   const float* __restrict__ mean,
                                                   const float* __restrict__ var,
                                                   const float* __restrict__ gamma,
                                                   const float* __restrict__ beta,
                                                   const float* __restrict__ W,
                                                   const float* __restrict__ b,
                                                   float* __restrict__ out) {
    int i = blockIdx.x, tid = threadIdx.x;
    __shared__ float t[CC];
    float v = fmaxf(h[(size_t)i * CC + tid], 0.f);
    t[tid] = (v - mean[tid]) * rsqrtf(var[tid] + BN_EPS) * gamma[tid] + beta[tid];
    __syncthreads();
    if (tid < OUTC) {
        float acc = b[tid];
        #pragma unroll 8
        for (int c = 0; c < CC; ++c) acc += t[c] * W[c * OUTC + tid];
        out[(size_t)i * OUTC + tid] = acc;
    }
}

// ---------------------------------------------------------------- fp32 GEMM
// C[M][N] = A[M][K] @ B[K][N], row-major, M,N multiples of 64, K multiple of 16.
// 64x64 tile, 256 threads, 4x4 per thread.
__global__ __launch_bounds__(256) void gemm_f32(const float* __restrict__ A,
                                                const float* __restrict__ B,
                                                float* __restrict__ C,
                                                int M, int N, int K,
                                                int lda, int ldb, int ldc) {
    __shared__ float As[16][72];  // [kk][m]
    __shared__ float Bs[16][72];  // [kk][n]
    const int tid = threadIdx.x;
    const int bm = blockIdx.x * 64;
    const int bn = blockIdx.y * 64;
    const int tx = tid & 15, ty = tid >> 4;

    const int ar = tid >> 2;          // A row within tile
    const int ak = (tid & 3) << 2;    // A k-offset
    const int bk = tid >> 4;          // B k-row
    const int bc = (tid & 15) << 2;   // B col-offset

    float acc[4][4] = {};

    for (int k0 = 0; k0 < K; k0 += 16) {
        const float4 av = *reinterpret_cast<const float4*>(
            &A[(size_t)(bm + ar) * lda + k0 + ak]);
        const float4 bv = *reinterpret_cast<const float4*>(
            &B[(size_t)(k0 + bk) * ldb + bn + bc]);
        __syncthreads();
        As[ak + 0][ar] = av.x;
        As[ak + 1][ar] = av.y;
        As[ak + 2][ar] = av.z;
        As[ak + 3][ar] = av.w;
        *reinterpret_cast<float4*>(&Bs[bk][bc]) = bv;
        __syncthreads();
        #pragma unroll
        for (int kk = 0; kk < 16; ++kk) {
            float4 a = *reinterpret_cast<const float4*>(&As[kk][ty << 2]);
            float4 b = *reinterpret_cast<const float4*>(&Bs[kk][tx << 2]);
            acc[0][0] += a.x * b.x; acc[0][1] += a.x * b.y;
            acc[0][2] += a.x * b.z; acc[0][3] += a.x * b.w;
            acc[1][0] += a.y * b.x; acc[1][1] += a.y * b.y;
            acc[1][2] += a.y * b.z; acc[1][3] += a.y * b.w;
            acc[2][0] += a.z * b.x; acc[2][1] += a.z * b.y;
            acc[2][2] += a.z * b.z; acc[2][3] += a.z * b.w;
            acc[3][0] += a.w * b.x; acc[3][1] += a.w * b.y;
            acc[3][2] += a.w * b.z; acc[3][3] += a.w * b.w;
        }
    }
    #pragma unroll
    for (int i = 0; i < 4; ++i) {
        float4 v = make_float4(acc[i][0], acc[i][1], acc[i][2], acc[i][3]);
        *reinterpret_cast<float4*>(
            &C[(size_t)(bm + (ty << 2) + i) * ldc + bn + (tx << 2)]) = v;
    }
}

// ---------------------------------------------------------------- fused pooling GEMM
// C[a][b] = sum_j A1[perm[a]][j] * A1[j][perm[b]],  A1 = A with unit diagonal,
// then C's own diagonal zeroed.  C is k x k (ldc=k), A is n x n, j over n.
// Gathers are folded into the tile loads: no Ap/Ac materialization.
__global__ __launch_bounds__(256) void gemm_pool(const float* __restrict__ A,
                                                 const int* __restrict__ perm,
                                                 float* __restrict__ C,
                                                 int k, int n) {
    __shared__ float As[16][72];
    __shared__ float Bs[16][72];
    const int tid = threadIdx.x;
    const int bm = blockIdx.x * 64;
    const int bn = blockIdx.y * 64;
    const int tx = tid & 15, ty = tid >> 4;

    const int ar = tid >> 2;
    const int ak = (tid & 3) << 2;
    const int bk = tid >> 4;
    const int bc = (tid & 15) << 2;

    const int pa  = perm[bm + ar];            // row gather index (hoisted)
    const int pc0 = perm[bn + bc + 0];        // col gather indices (hoisted)
    const int pc1 = perm[bn + bc + 1];
    const int pc2 = perm[bn + bc + 2];
    const int pc3 = perm[bn + bc + 3];

    float acc[4][4] = {};

    for (int k0 = 0; k0 < n; k0 += 16) {
        // A-tile: row perm[bm+ar], cols k0+ak..+3 (coalesced float4), A1 diag fix
        float4 av = *reinterpret_cast<const float4*>(&A[(size_t)pa * n + k0 + ak]);
        if (k0 + ak + 0 == pa) av.x = 1.f;
        if (k0 + ak + 1 == pa) av.y = 1.f;
        if (k0 + ak + 2 == pa) av.z = 1.f;
        if (k0 + ak + 3 == pa) av.w = 1.f;
        // B-tile: row j=k0+bk, cols perm[bn+bc..+3] (scalar gathers), A1 diag fix
        const int jrow = k0 + bk;
        const size_t jb = (size_t)jrow * n;
        float b0 = (jrow == pc0) ? 1.f : A[jb + pc0];
        float b1 = (jrow == pc1) ? 1.f : A[jb + pc1];
        float b2 = (jrow == pc2) ? 1.f : A[jb + pc2];
        float b3 = (jrow == pc3) ? 1.f : A[jb + pc3];
        __syncthreads();
        As[ak + 0][ar] = av.x;
        As[ak + 1][ar] = av.y;
        As[ak + 2][ar] = av.z;
        As[ak + 3][ar] = av.w;
        Bs[bk][bc + 0] = b0;
        Bs[bk][bc + 1] = b1;
        Bs[bk][bc + 2] = b2;
        Bs[bk][bc + 3] = b3;
        __syncthreads();
        #pragma unroll
        for (int kk = 0; kk < 16; ++kk) {
            float4 a = *reinterpret_cast<const float4*>(&As[kk][ty << 2]);
            float4 b = *reinterpret_cast<const float4*>(&Bs[kk][tx << 2]);
            acc[0][0] += a.x * b.x; acc[0][1] += a.x * b.y;
            acc[0][2] += a.x * b.z; acc[0][3] += a.x * b.w;
            acc[1][0] += a.y * b.x; acc[1][1] += a.y * b.y;
            acc[1][2] += a.y * b.z; acc[1][3] += a.y * b.w;
            acc[2][0] += a.z * b.x; acc[2][1] += a.z * b.y;
            acc[2][2] += a.z * b.z; acc[2][3] += a.z * b.w;
            acc[3][0] += a.w * b.x; acc[3][1] += a.w * b.y;
            acc[3][2] += a.w * b.z; acc[3][3] += a.w * b.w;
        }
    }
    #pragma unroll
    for (int i = 0; i < 4; ++i) {
        const int ga = bm + (ty << 2) + i;
        const int gb = bn + (tx << 2);
        float4 v;
        v.x = (ga == gb + 0) ? 0.f : acc[i][0];   // zero output diagonal
        v.y = (ga == gb + 1) ? 0.f : acc[i][1];
        v.z = (ga == gb + 2) ? 0.f : acc[i][2];
        v.w = (ga == gb + 3) ? 0.f : acc[i][3];
        *reinterpret_cast<float4*>(&C[(size_t)ga * k + gb]) = v;
    }
}

// ---------------------------------------------------------------- host-side helpers

static void gcn(const float* A, int n, const float* x, const float* W,
                const float* bias, float* out, int do_relu,
                float* xw, float* z, float* dis, float* selfw,
                hipStream_t stream) {
    k_degree<<<n, 256, 0, stream>>>(A, dis, selfw, n);
    gemm_f32<<<dim3(n / 64, CC / 64), 256, 0, stream>>>(x, W, xw, n, CC, CC, CC, CC, CC);
    k_scale_rows<<<n, 256, 0, stream>>>(xw, dis);                  // xw := y
    gemm_f32<<<dim3(n / 64, CC / 64), 256, 0, stream>>>(A, xw, z, n, CC, n, n, CC, CC);
    k_gcn_epilogue<<<n, 256, 0, stream>>>(z, xw, dis, selfw, bias, out, do_relu);
}

extern "C" void kernel_launch(void* const* d_in, const int* in_sizes, int n_in,
                              void* d_out, int out_size, void* d_ws, size_t ws_size,
                              hipStream_t stream) {
    const float* x       = (const float*)d_in[0];
    const int*   ei      = (const int*)d_in[1];
    const float* down_W  = (const float*)d_in[2];   // (4,256,256)
    const float* down_b  = (const float*)d_in[3];   // (4,256)
    const float* pool_w  = (const float*)d_in[4];   // (3,256)
    const float* up_W    = (const float*)d_in[5];   // (3,256,256)
    const float* up_b    = (const float*)d_in[6];   // (3,256)
    const float* bn_g    = (const float*)d_in[7];
    const float* bn_b    = (const float*)d_in[8];
    const float* lin_W   = (const float*)d_in[9];   // (256,16)
    const float* lin_b   = (const float*)d_in[10];  // (16)
    float* out = (float*)d_out;

    // ---- workspace carve-up (256B aligned). Peak ≈ 108 MB. ----
    char* w = (char*)d_ws;
    auto alloc = [&](size_t bytes) -> float* {
        float* p = (float*)w;
        w += (bytes + 255) & ~(size_t)255;
        return p;
    };
    float* A0   = alloc((size_t)NN * NN * 4);        // 64 MB (live whole run)
    float* cA1  = alloc((size_t)2048 * 2048 * 4);    // 16 MB
    float* cA2  = alloc((size_t)1024 * 1024 * 4);    // 4 MB
    float* cA3  = alloc((size_t)512 * 512 * 4);      // 1 MB
    float* h0   = alloc((size_t)NN * CC * 4);        // 4 MB
    float* h1   = alloc((size_t)2048 * CC * 4);      // 2 MB
    float* h2   = alloc((size_t)1024 * CC * 4);      // 1 MB
    float* tA   = alloc((size_t)NN * CC * 4);        // 4 MB
    float* tB   = alloc((size_t)NN * CC * 4);        // 4 MB
    float* xw   = alloc((size_t)NN * CC * 4);        // 4 MB
    float* zbuf = alloc((size_t)NN * CC * 4);        // 4 MB
    float* dis   = alloc(NN * 4);
    float* selfw = alloc(NN * 4);
    float* score = alloc(NN * 4);
    float* vals  = alloc(NN * 4);
    float* invn  = alloc(256);
    float* meanb = alloc(CC * 4);
    float* varb  = alloc(CC * 4);
    int* perm0 = (int*)alloc(2048 * 4);
    int* perm1 = (int*)alloc(1024 * 4);
    int* perm2 = (int*)alloc(512 * 4);
    (void)ws_size; (void)n_in; (void)in_sizes; (void)out_size;

    // ---- build dense adjacency ----
    k_zero<<<2048, 256, 0, stream>>>(A0, (size_t)NN * NN);
    k_build_adj<<<EE / 256, 256, 0, stream>>>(ei, A0);

    // ---- down conv 0 (4096) ----
    gcn(A0, NN, x, down_W, down_b, h0, 1, xw, zbuf, dis, selfw, stream);

    // ---- level 0 pooling: 4096 -> 2048 ----
    k_wnorm<<<1, 256, 0, stream>>>(pool_w, invn);
    k_score<<<NN, 256, 0, stream>>>(h0, pool_w, invn, score);
    k_topk<<<NN / 256, 256, NN * 4, stream>>>(score, NN, 2048, perm0, vals);
    k_gate<<<2048, 256, 0, stream>>>(h0, perm0, vals, tA);
    gemm_pool<<<dim3(2048 / 64, 2048 / 64), 256, 0, stream>>>(A0, perm0, cA1, 2048, NN);
    gcn(cA1, 2048, tA, down_W + 1 * CC * CC, down_b + 1 * CC, h1, 1,
        xw, zbuf, dis, selfw, stream);

    // ---- level 1 pooling: 2048 -> 1024 ----
    k_wnorm<<<1, 256, 0, stream>>>(pool_w + CC, invn);
    k_score<<<2048, 256, 0, stream>>>(h1, pool_w + CC, invn, score);
    k_topk<<<2048 / 256, 256, 2048 * 4, stream>>>(score, 2048, 1024, perm1, vals);
    k_gate<<<1024, 256, 0, stream>>>(h1, perm1, vals, tA);
    gemm_pool<<<dim3(1024 / 64, 1024 / 64), 256, 0, stream>>>(cA1, perm1, cA2, 1024, 2048);
    gcn(cA2, 1024, tA, down_W + 2 * CC * CC, down_b + 2 * CC, h2, 1,
        xw, zbuf, dis, selfw, stream);

    // ---- level 2 pooling: 1024 -> 512 ----
    k_wnorm<<<1, 256, 0, stream>>>(pool_w + 2 * CC, invn);
    k_score<<<1024, 256, 0, stream>>>(h2, pool_w + 2 * CC, invn, score);
    k_topk<<<1024 / 256, 256, 1024 * 4, stream>>>(score, 1024, 512, perm2, vals);
    k_gate<<<512, 256, 0, stream>>>(h2, perm2, vals, tA);
    gemm_pool<<<dim3(512 / 64, 512 / 64), 256, 0, stream>>>(cA2, perm2, cA3, 512, 1024);
    gcn(cA3, 512, tA, down_W + 3 * CC * CC, down_b + 3 * CC, tB, 1,
        xw, zbuf, dis, selfw, stream);

    // ---- up path ----
    // i=0: res=h2 (1024), perm2
    hipMemcpyAsync(tA, h2, (size_t)1024 * CC * 4, hipMemcpyDeviceToDevice, stream);
    k_scatter_add<<<512, 256, 0, stream>>>(tA, tB, perm2);
    gcn(cA2, 1024, tA, up_W, up_b, tB, 1, xw, zbuf, dis, selfw, stream);
    // i=1: res=h1 (2048), perm1
    hipMemcpyAsync(tA, h1, (size_t)2048 * CC * 4, hipMemcpyDeviceToDevice, stream);
    k_scatter_add<<<1024, 256, 0, stream>>>(tA, tB, perm1);
    gcn(cA1, 2048, tA, up_W + 1 * CC * CC, up_b + 1 * CC, tB, 1,
        xw, zbuf, dis, selfw, stream);
    // i=2: res=h0 (4096), perm0, no relu
    hipMemcpyAsync(tA, h0, (size_t)NN * CC * 4, hipMemcpyDeviceToDevice, stream);
    k_scatter_add<<<2048, 256, 0, stream>>>(tA, tB, perm0);
    gcn(A0, NN, tA, up_W + 2 * CC * CC, up_b + 2 * CC, tB, 0,
        xw, zbuf, dis, selfw, stream);

    // ---- final relu + batchnorm + linear ----
    k_bn_stats<<<CC, 256, 0, stream>>>(tB, meanb, varb, NN);
    k_bn_linear<<<NN, 256, 0, stream>>>(tB, meanb, varb, bn_g, bn_b, lin_W, lin_b, out);
}

// Round 7
// 1991.525 us; speedup vs baseline: 1.8097x; 1.8097x over previous
//
#include <hip/hip_runtime.h>
#include <cstdint>
#include <cstddef>

#define NN 4096
#define CC 256
#define EE 131072
#define OUTC 16
#define BN_EPS 1e-5f

typedef __attribute__((ext_vector_type(8))) short short8v;
typedef __attribute__((ext_vector_type(4))) float floatx4;

__device__ __forceinline__ float b2f(ushort u) {
    return __uint_as_float(((unsigned)u) << 16);
}
__device__ __forceinline__ ushort f2b(float f) {
    unsigned u = __float_as_uint(f);
    unsigned r = (u + 0x7FFFu + ((u >> 16) & 1u)) >> 16;
    return (ushort)r;
}

// ---------------------------------------------------------------- small kernels

__global__ __launch_bounds__(256) void k_zero(float* __restrict__ p, size_t n) {
    size_t i = (size_t)blockIdx.x * blockDim.x + threadIdx.x;
    size_t stride = (size_t)gridDim.x * blockDim.x;
    for (; i < n; i += stride) p[i] = 0.f;
}

__global__ __launch_bounds__(256) void k_build_adj(const int* __restrict__ ei,
                                                   float* __restrict__ A) {
    int e = blockIdx.x * blockDim.x + threadIdx.x;
    if (e < EE) {
        int s = ei[e];        // source
        int t = ei[EE + e];   // target
        atomicAdd(&A[(size_t)t * NN + s], 1.0f);
    }
}

// fp32 -> bf16 elementwise convert (count multiple of 4)
__global__ __launch_bounds__(256) void k_f2b(const float* __restrict__ in,
                                             ushort* __restrict__ out, size_t cnt4) {
    size_t i = (size_t)blockIdx.x * blockDim.x + threadIdx.x;
    if (i < cnt4) {
        float4 v = *reinterpret_cast<const float4*>(&in[i * 4]);
        ushort4 o;
        o.x = f2b(v.x); o.y = f2b(v.y); o.z = f2b(v.z); o.w = f2b(v.w);
        *reinterpret_cast<ushort4*>(&out[i * 4]) = o;
    }
}

// degree from fp32 adjacency
__global__ __launch_bounds__(256) void k_degree(const float* __restrict__ A,
                                                float* __restrict__ dis,
                                                float* __restrict__ selfw, int n) {
    int i = blockIdx.x;
    int tid = threadIdx.x;
    const float* row = A + (size_t)i * n;
    float s = 0.f;
    for (int j = tid; j < n; j += 256) s += row[j];
    __shared__ float ss[256];
    ss[tid] = s;
    __syncthreads();
    for (int off = 128; off > 0; off >>= 1) {
        if (tid < off) ss[tid] += ss[tid + off];
        __syncthreads();
    }
    if (tid == 0) {
        float d0 = row[i];
        float e = (d0 > 0.f) ? 0.f : 2.f;
        dis[i] = rsqrtf(ss[0] + e);
        selfw[i] = e;
    }
}

// degree from bf16 adjacency (vectorized short8 loads)
__global__ __launch_bounds__(256) void k_degree_bf(const ushort* __restrict__ Ah,
                                                   float* __restrict__ dis,
                                                   float* __restrict__ selfw, int n) {
    int i = blockIdx.x;
    int tid = threadIdx.x;
    const ushort* row = Ah + (size_t)i * n;
    float s = 0.f;
    int nc = n >> 3;
    for (int c = tid; c < nc; c += 256) {
        int4 v = *reinterpret_cast<const int4*>(row + c * 8);
        const ushort* u = (const ushort*)&v;
        #pragma unroll
        for (int m = 0; m < 8; ++m) s += b2f(u[m]);
    }
    __shared__ float ss[256];
    ss[tid] = s;
    __syncthreads();
    for (int off = 128; off > 0; off >>= 1) {
        if (tid < off) ss[tid] += ss[tid + off];
        __syncthreads();
    }
    if (tid == 0) {
        float d0 = b2f(row[i]);
        float e = (d0 > 0.f) ? 0.f : 2.f;
        dis[i] = rsqrtf(ss[0] + e);
        selfw[i] = e;
    }
}

// xw[i][c] *= dis[i]   (xw becomes y = dis ⊙ (x@W))
__global__ __launch_bounds__(256) void k_scale_rows(float* __restrict__ xw,
                                                    const float* __restrict__ dis) {
    int i = blockIdx.x, c = threadIdx.x;
    xw[(size_t)i * CC + c] *= dis[i];
}

// out = [relu]( dis_i * (z + selfw_i * y) + b )
__global__ __launch_bounds__(256) void k_gcn_epilogue(const float* __restrict__ z,
                                                      const float* __restrict__ y,
                                                      const float* __restrict__ dis,
                                                      const float* __restrict__ selfw,
                                                      const float* __restrict__ bias,
                                                      float* __restrict__ out,
                                                      int do_relu) {
    int i = blockIdx.x, c = threadIdx.x;
    float di = dis[i];
    float v = di * (z[(size_t)i * CC + c] + selfw[i] * y[(size_t)i * CC + c]) + bias[c];
    if (do_relu) v = fmaxf(v, 0.f);
    out[(size_t)i * CC + c] = v;
}

__global__ __launch_bounds__(256) void k_wnorm(const float* __restrict__ w,
                                               float* __restrict__ invn) {
    __shared__ float ss[256];
    int tid = threadIdx.x;
    float v = w[tid];
    ss[tid] = v * v;
    __syncthreads();
    for (int off = 128; off > 0; off >>= 1) {
        if (tid < off) ss[tid] += ss[tid + off];
        __syncthreads();
    }
    if (tid == 0) invn[0] = rsqrtf(ss[0]);
}

__global__ __launch_bounds__(256) void k_score(const float* __restrict__ h,
                                               const float* __restrict__ w,
                                               const float* __restrict__ invn,
                                               float* __restrict__ score) {
    int i = blockIdx.x, tid = threadIdx.x;
    __shared__ float ss[256];
    ss[tid] = h[(size_t)i * CC + tid] * w[tid];
    __syncthreads();
    for (int off = 128; off > 0; off >>= 1) {
        if (tid < off) ss[tid] += ss[tid + off];
        __syncthreads();
    }
    if (tid == 0) score[i] = tanhf(ss[0] * invn[0]);
}

// rank[i] = #{s_j > s_i} + #{s_j==s_i, j<i}  (PyG topk tie-break)
__global__ __launch_bounds__(256) void k_rank(const float* __restrict__ score, int n,
                                              int* __restrict__ rank) {
    extern __shared__ float sc[];
    int tid = threadIdx.x;
    for (int j = tid; j < n; j += 256) sc[j] = score[j];
    __syncthreads();
    int i = blockIdx.x * 256 + tid;
    if (i < n) {
        float s = sc[i];
        int rk = 0;
        for (int j = 0; j < n; ++j) {
            float sj = sc[j];
            rk += (sj > s) || (sj == s && j < i);
        }
        rank[i] = rk;
    }
}

// selected nodes (rank<k) compacted in ASCENDING INDEX order
__global__ __launch_bounds__(256) void k_sortsel(const float* __restrict__ score,
                                                 const int* __restrict__ rank,
                                                 int n, int k, int* __restrict__ sperm,
                                                 float* __restrict__ svals) {
    extern __shared__ int sr[];
    int tid = threadIdx.x;
    for (int j = tid; j < n; j += 256) sr[j] = (rank[j] < k) ? 1 : 0;
    __syncthreads();
    int i = blockIdx.x * 256 + tid;
    if (i < n && sr[i]) {
        int pos = 0;
        for (int j = 0; j < i; ++j) pos += sr[j];
        sperm[pos] = i;
        svals[pos] = score[i];
    }
}

// out[a][c] = h[sperm[a]][c] * svals[a]
__global__ __launch_bounds__(256) void k_gate(const float* __restrict__ h,
                                              const int* __restrict__ perm,
                                              const float* __restrict__ vals,
                                              float* __restrict__ out) {
    int a = blockIdx.x, c = threadIdx.x;
    out[(size_t)a * CC + c] = h[(size_t)perm[a] * CC + c] * vals[a];
}

__global__ __launch_bounds__(256) void k_scatter_add(float* __restrict__ dst,
                                                     const float* __restrict__ src,
                                                     const int* __restrict__ perm) {
    int a = blockIdx.x, c = threadIdx.x;
    dst[(size_t)perm[a] * CC + c] += src[(size_t)a * CC + c];
}

__global__ __launch_bounds__(256) void k_bn_stats(const float* __restrict__ h,
                                                  float* __restrict__ mean,
                                                  float* __restrict__ var, int n) {
    int c = blockIdx.x, tid = threadIdx.x;
    float s = 0.f, s2 = 0.f;
    for (int r = tid; r < n; r += 256) {
        float v = fmaxf(h[(size_t)r * CC + c], 0.f);
        s += v;
        s2 += v * v;
    }
    __shared__ float ss[256], ss2[256];
    ss[tid] = s;
    ss2[tid] = s2;
    __syncthreads();
    for (int off = 128; off > 0; off >>= 1) {
        if (tid < off) { ss[tid] += ss[tid + off]; ss2[tid] += ss2[tid + off]; }
        __syncthreads();
    }
    if (tid == 0) {
        float m = ss[0] / n;
        mean[c] = m;
        var[c] = ss2[0] / n - m * m;
    }
}

__global__ __launch_bounds__(256) void k_bn_linear(const float* __restrict__ h,
                                                   const float* __restrict__ mean,
                                                   const float* __restrict__ var,
                                                   const float* __restrict__ gamma,
                                                   const float* __restrict__ beta,
                                                   const float* __restrict__ W,
                                                   const float* __restrict__ b,
                                                   float* __restrict__ out) {
    int i = blockIdx.x, tid = threadIdx.x;
    __shared__ float t[CC];
    float v = fmaxf(h[(size_t)i * CC + tid], 0.f);
    t[tid] = (v - mean[tid]) * rsqrtf(var[tid] + BN_EPS) * gamma[tid] + beta[tid];
    __syncthreads();
    if (tid < OUTC) {
        float acc = b[tid];
        #pragma unroll 8
        for (int c = 0; c < CC; ++c) acc += t[c] * W[c * OUTC + tid];
        out[(size_t)i * OUTC + tid] = acc;
    }
}

// y (n x 256 fp32) -> yT (256 x 2n bf16): cols [0,n)=hi split, [n,2n)=lo split
__global__ __launch_bounds__(256) void k_ysplit(const float* __restrict__ y,
                                                ushort* __restrict__ yT, int n) {
    __shared__ float L[64][65];
    int t = threadIdx.x;
    int i0 = blockIdx.x * 64, c0 = blockIdx.y * 64;
    #pragma unroll
    for (int e = 0; e < 16; ++e) {
        int idx = e * 256 + t;
        int c = idx & 63, r = idx >> 6;
        L[r][c] = y[(size_t)(i0 + r) * CC + c0 + c];
    }
    __syncthreads();
    #pragma unroll
    for (int e = 0; e < 16; ++e) {
        int idx = e * 256 + t;
        int ii = idx & 63, cc = idx >> 6;
        float v = L[ii][cc];
        ushort hi = f2b(v);
        float lo = v - b2f(hi);
        size_t base = (size_t)(c0 + cc) * (size_t)(2 * n) + i0 + ii;
        yT[base] = hi;
        yT[base + n] = f2b(lo);
    }
}

// BpT[b][j] = (j==ps[b]) ? 1 : Ah[j][ps[b]]   (gather-transpose with A1 diag)
__global__ __launch_bounds__(256) void k_bpt(const ushort* __restrict__ Ah,
                                             const int* __restrict__ ps,
                                             ushort* __restrict__ BpT, int n) {
    __shared__ ushort L[64][65];
    __shared__ int pcols[64];
    int t = threadIdx.x;
    int b0 = blockIdx.x * 64, j0 = blockIdx.y * 64;
    if (t < 64) pcols[t] = ps[b0 + t];
    __syncthreads();
    #pragma unroll
    for (int e = 0; e < 16; ++e) {
        int idx = e * 256 + t;
        int c = idx & 63, r = idx >> 6;
        L[r][c] = Ah[(size_t)(j0 + r) * n + pcols[c]];
    }
    __syncthreads();
    #pragma unroll
    for (int e = 0; e < 16; ++e) {
        int idx = e * 256 + t;
        int jj = idx & 63, bb = idx >> 6;
        ushort v = L[jj][bb];
        if (j0 + jj == pcols[bb]) v = 0x3F80;   // bf16(1.0)
        BpT[(size_t)(b0 + bb) * n + j0 + jj] = v;
    }
}

// ---------------------------------------------------------------- bf16 MFMA GEMM
// C[M][N] = A'[M][K] @ B[K][N] with BT (N x K row-major) given.
// A'[i][k] = A[permA?permA[i]:i][k & kmask], optionally patched A1-diag (j==pa -> 1).
// 4 waves (2x2), BN=128 fixed, BK=32, 16x16x32 bf16 MFMA, reg-staged LDS (pad 40).
template<int BM>
__global__ __launch_bounds__(256) void gemm_bf16(
    const ushort* __restrict__ A, const int* __restrict__ permA, unsigned kmask,
    int diagA, const ushort* __restrict__ BT, float* __restrict__ C,
    int M, int N, int K, int lda, int ldbt, int ldc, int zero_diag)
{
    constexpr int BK = 32;
    constexpr int WM = BM / 2;
    constexpr int FM = WM / 16;
    constexpr int FN = 4;              // WN = 64
    constexpr int AP = BM / 64;        // A staging passes
    __shared__ ushort As[BM][40];
    __shared__ ushort Bs[128][40];
    const int tid = threadIdx.x;
    const int lane = tid & 63;
    const int w = tid >> 6;
    const int wr = w >> 1, wc = w & 1;
    const int bm = blockIdx.x * BM, bn = blockIdx.y * 128;
    const int srow = tid >> 2;         // 0..63
    const int schk = tid & 3;          // 16B chunk within 64B row

    int arow[AP];
    const ushort* aptr[AP];
    #pragma unroll
    for (int p = 0; p < AP; ++p) {
        int gr = bm + srow + p * 64;
        int pa = permA ? permA[gr] : gr;
        arow[p] = pa;
        aptr[p] = A + (size_t)pa * lda;
    }
    const ushort* bptr[2];
    #pragma unroll
    for (int p = 0; p < 2; ++p)
        bptr[p] = BT + (size_t)(bn + srow + p * 64) * ldbt;

    floatx4 acc[FM][FN];
    #pragma unroll
    for (int i = 0; i < FM; ++i)
        #pragma unroll
        for (int j = 0; j < FN; ++j) {
            floatx4 z4 = {0.f, 0.f, 0.f, 0.f};
            acc[i][j] = z4;
        }

    int4 ra[AP], rb[2];
    // preload k0 = 0
    {
        const int jb = schk * 8;
        const int jm = (int)((unsigned)jb & kmask);
        #pragma unroll
        for (int p = 0; p < AP; ++p) {
            ra[p] = *reinterpret_cast<const int4*>(aptr[p] + jm);
            if (diagA) {
                int d = arow[p] - jm;
                if (d >= 0 && d < 8) ((ushort*)&ra[p])[d] = 0x3F80;
            }
        }
        #pragma unroll
        for (int p = 0; p < 2; ++p)
            rb[p] = *reinterpret_cast<const int4*>(bptr[p] + jb);
    }

    for (int k0 = 0; k0 < K; k0 += BK) {
        __syncthreads();
        #pragma unroll
        for (int p = 0; p < AP; ++p)
            *reinterpret_cast<int4*>(&As[srow + p * 64][schk * 8]) = ra[p];
        #pragma unroll
        for (int p = 0; p < 2; ++p)
            *reinterpret_cast<int4*>(&Bs[srow + p * 64][schk * 8]) = rb[p];
        __syncthreads();
        if (k0 + BK < K) {
            const int jb = k0 + BK + schk * 8;
            const int jm = (int)((unsigned)jb & kmask);
            #pragma unroll
            for (int p = 0; p < AP; ++p) {
                ra[p] = *reinterpret_cast<const int4*>(aptr[p] + jm);
                if (diagA) {
                    int d = arow[p] - jm;
                    if (d >= 0 && d < 8) ((ushort*)&ra[p])[d] = 0x3F80;
                }
            }
            #pragma unroll
            for (int p = 0; p < 2; ++p)
                rb[p] = *reinterpret_cast<const int4*>(bptr[p] + jb);
        }
        const int k8 = (lane >> 4) * 8;
        const int l15 = lane & 15;
        short8v a[FM], b[FN];
        #pragma unroll
        for (int j = 0; j < FN; ++j)
            b[j] = *reinterpret_cast<const short8v*>(&Bs[wc * 64 + j * 16 + l15][k8]);
        #pragma unroll
        for (int i = 0; i < FM; ++i)
            a[i] = *reinterpret_cast<const short8v*>(&As[wr * WM + i * 16 + l15][k8]);
        #pragma unroll
        for (int i = 0; i < FM; ++i)
            #pragma unroll
            for (int j = 0; j < FN; ++j)
                acc[i][j] = __builtin_amdgcn_mfma_f32_16x16x32_bf16(
                    a[i], b[j], acc[i][j], 0, 0, 0);
    }

    // epilogue: C/D layout col=lane&15, row=(lane>>4)*4+reg
    #pragma unroll
    for (int i = 0; i < FM; ++i) {
        #pragma unroll
        for (int j = 0; j < FN; ++j) {
            int gcol = bn + wc * 64 + j * 16 + (lane & 15);
            #pragma unroll
            for (int r = 0; r < 4; ++r) {
                int grow = bm + wr * WM + i * 16 + (lane >> 4) * 4 + r;
                float v = acc[i][j][r];
                if (zero_diag && grow == gcol) v = 0.f;
                C[(size_t)grow * ldc + gcol] = v;
            }
        }
    }
}

// ---------------------------------------------------------------- fp32 GEMM (small)
__global__ __launch_bounds__(256) void gemm_f32(const float* __restrict__ A,
                                                const float* __restrict__ B,
                                                float* __restrict__ C,
                                                int M, int N, int K,
                                                int lda, int ldb, int ldc) {
    __shared__ float As[16][72];
    __shared__ float Bs[16][72];
    const int tid = threadIdx.x;
    const int bm = blockIdx.x * 64;
    const int bn = blockIdx.y * 64;
    const int tx = tid & 15, ty = tid >> 4;
    const int ar = tid >> 2;
    const int ak = (tid & 3) << 2;
    const int bk = tid >> 4;
    const int bc = (tid & 15) << 2;
    float acc[4][4] = {};
    for (int k0 = 0; k0 < K; k0 += 16) {
        const float4 av = *reinterpret_cast<const float4*>(
            &A[(size_t)(bm + ar) * lda + k0 + ak]);
        const float4 bv = *reinterpret_cast<const float4*>(
            &B[(size_t)(k0 + bk) * ldb + bn + bc]);
        __syncthreads();
        As[ak + 0][ar] = av.x;
        As[ak + 1][ar] = av.y;
        As[ak + 2][ar] = av.z;
        As[ak + 3][ar] = av.w;
        *reinterpret_cast<float4*>(&Bs[bk][bc]) = bv;
        __syncthreads();
        #pragma unroll
        for (int kk = 0; kk < 16; ++kk) {
            float4 a = *reinterpret_cast<const float4*>(&As[kk][ty << 2]);
            float4 b = *reinterpret_cast<const float4*>(&Bs[kk][tx << 2]);
            acc[0][0] += a.x * b.x; acc[0][1] += a.x * b.y;
            acc[0][2] += a.x * b.z; acc[0][3] += a.x * b.w;
            acc[1][0] += a.y * b.x; acc[1][1] += a.y * b.y;
            acc[1][2] += a.y * b.z; acc[1][3] += a.y * b.w;
            acc[2][0] += a.z * b.x; acc[2][1] += a.z * b.y;
            acc[2][2] += a.z * b.z; acc[2][3] += a.z * b.w;
            acc[3][0] += a.w * b.x; acc[3][1] += a.w * b.y;
            acc[3][2] += a.w * b.z; acc[3][3] += a.w * b.w;
        }
    }
    #pragma unroll
    for (int i = 0; i < 4; ++i) {
        float4 v = make_float4(acc[i][0], acc[i][1], acc[i][2], acc[i][3]);
        *reinterpret_cast<float4*>(
            &C[(size_t)(bm + (ty << 2) + i) * ldc + bn + (tx << 2)]) = v;
    }
}

// fused fp32 pooling GEMM (level-2 only; sorted perm -> decent locality)
__global__ __launch_bounds__(256) void gemm_pool(const float* __restrict__ A,
                                                 const int* __restrict__ perm,
                                                 float* __restrict__ C,
                                                 int k, int n) {
    __shared__ float As[16][72];
    __shared__ float Bs[16][72];
    const int tid = threadIdx.x;
    const int bm = blockIdx.x * 64;
    const int bn = blockIdx.y * 64;
    const int tx = tid & 15, ty = tid >> 4;
    const int ar = tid >> 2;
    const int ak = (tid & 3) << 2;
    const int bk = tid >> 4;
    const int bc = (tid & 15) << 2;
    const int pa  = perm[bm + ar];
    const int pc0 = perm[bn + bc + 0];
    const int pc1 = perm[bn + bc + 1];
    const int pc2 = perm[bn + bc + 2];
    const int pc3 = perm[bn + bc + 3];
    float acc[4][4] = {};
    for (int k0 = 0; k0 < n; k0 += 16) {
        float4 av = *reinterpret_cast<const float4*>(&A[(size_t)pa * n + k0 + ak]);
        if (k0 + ak + 0 == pa) av.x = 1.f;
        if (k0 + ak + 1 == pa) av.y = 1.f;
        if (k0 + ak + 2 == pa) av.z = 1.f;
        if (k0 + ak + 3 == pa) av.w = 1.f;
        const int jrow = k0 + bk;
        const size_t jb = (size_t)jrow * n;
        float b0 = (jrow == pc0) ? 1.f : A[jb + pc0];
        float b1 = (jrow == pc1) ? 1.f : A[jb + pc1];
        float b2 = (jrow == pc2) ? 1.f : A[jb + pc2];
        float b3 = (jrow == pc3) ? 1.f : A[jb + pc3];
        __syncthreads();
        As[ak + 0][ar] = av.x;
        As[ak + 1][ar] = av.y;
        As[ak + 2][ar] = av.z;
        As[ak + 3][ar] = av.w;
        Bs[bk][bc + 0] = b0;
        Bs[bk][bc + 1] = b1;
        Bs[bk][bc + 2] = b2;
        Bs[bk][bc + 3] = b3;
        __syncthreads();
        #pragma unroll
        for (int kk = 0; kk < 16; ++kk) {
            float4 a = *reinterpret_cast<const float4*>(&As[kk][ty << 2]);
            float4 b = *reinterpret_cast<const float4*>(&Bs[kk][tx << 2]);
            acc[0][0] += a.x * b.x; acc[0][1] += a.x * b.y;
            acc[0][2] += a.x * b.z; acc[0][3] += a.x * b.w;
            acc[1][0] += a.y * b.x; acc[1][1] += a.y * b.y;
            acc[1][2] += a.y * b.z; acc[1][3] += a.y * b.w;
            acc[2][0] += a.z * b.x; acc[2][1] += a.z * b.y;
            acc[2][2] += a.z * b.z; acc[2][3] += a.z * b.w;
            acc[3][0] += a.w * b.x; acc[3][1] += a.w * b.y;
            acc[3][2] += a.w * b.z; acc[3][3] += a.w * b.w;
        }
    }
    #pragma unroll
    for (int i = 0; i < 4; ++i) {
        const int ga = bm + (ty << 2) + i;
        const int gb = bn + (tx << 2);
        float4 v;
        v.x = (ga == gb + 0) ? 0.f : acc[i][0];
        v.y = (ga == gb + 1) ? 0.f : acc[i][1];
        v.z = (ga == gb + 2) ? 0.f : acc[i][2];
        v.w = (ga == gb + 3) ? 0.f : acc[i][3];
        *reinterpret_cast<float4*>(&C[(size_t)ga * k + gb]) = v;
    }
}

// ---------------------------------------------------------------- host-side helpers

// GCN with bf16-MFMA aggregation: z = Ah @ (yh + yl), K = 2n trick
static void gcn_bf(const ushort* Ah, int n, const float* xin, const float* W,
                   const float* bias, float* outp, int relu,
                   float* xw, float* zbuf, ushort* yT, float* dis, float* selfw,
                   hipStream_t s) {
    k_degree_bf<<<n, 256, 0, s>>>(Ah, dis, selfw, n);
    gemm_f32<<<dim3(n / 64, 4), 256, 0, s>>>(xin, W, xw, n, CC, CC, CC, CC, CC);
    k_scale_rows<<<n, 256, 0, s>>>(xw, dis);
    k_ysplit<<<dim3(n / 64, 4), 256, 0, s>>>(xw, yT, n);
    gemm_bf16<64><<<dim3(n / 64, 2), 256, 0, s>>>(
        Ah, nullptr, (unsigned)(n - 1), 0, yT, zbuf,
        n, CC, 2 * n, n, 2 * n, CC, 0);
    k_gcn_epilogue<<<n, 256, 0, s>>>(zbuf, xw, dis, selfw, bias, outp, relu);
}

// fp32 GCN (small levels)
static void gcn_f32(const float* A, int n, const float* xin, const float* W,
                    const float* bias, float* outp, int relu,
                    float* xw, float* zbuf, float* dis, float* selfw,
                    hipStream_t s) {
    k_degree<<<n, 256, 0, s>>>(A, dis, selfw, n);
    gemm_f32<<<dim3(n / 64, 4), 256, 0, s>>>(xin, W, xw, n, CC, CC, CC, CC, CC);
    k_scale_rows<<<n, 256, 0, s>>>(xw, dis);
    gemm_f32<<<dim3(n / 64, 4), 256, 0, s>>>(A, xw, zbuf, n, CC, n, n, CC, CC);
    k_gcn_epilogue<<<n, 256, 0, s>>>(zbuf, xw, dis, selfw, bias, outp, relu);
}

// scoring + sorted top-k selection
static void select_sorted(const float* h, const float* pw, int n, int k,
                          float* invn, float* score, int* rank,
                          int* sperm, float* svals, hipStream_t s) {
    k_wnorm<<<1, 256, 0, s>>>(pw, invn);
    k_score<<<n, 256, 0, s>>>(h, pw, invn, score);
    k_rank<<<(n + 255) / 256, 256, n * 4, s>>>(score, n, rank);
    k_sortsel<<<(n + 255) / 256, 256, n * 4, s>>>(score, rank, n, k, sperm, svals);
}

extern "C" void kernel_launch(void* const* d_in, const int* in_sizes, int n_in,
                              void* d_out, int out_size, void* d_ws, size_t ws_size,
                              hipStream_t stream) {
    const float* x       = (const float*)d_in[0];
    const int*   ei      = (const int*)d_in[1];
    const float* down_W  = (const float*)d_in[2];
    const float* down_b  = (const float*)d_in[3];
    const float* pool_w  = (const float*)d_in[4];
    const float* up_W    = (const float*)d_in[5];
    const float* up_b    = (const float*)d_in[6];
    const float* bn_g    = (const float*)d_in[7];
    const float* bn_b    = (const float*)d_in[8];
    const float* lin_W   = (const float*)d_in[9];
    const float* lin_b   = (const float*)d_in[10];
    float* out = (float*)d_out;
    (void)ws_size; (void)n_in; (void)in_sizes; (void)out_size;

    // ---- workspace layout (lifetime-overlaid), peak ~96.2 MB ----
    const size_t MB = 1ull << 20;
    char* S = (char*)d_ws;
    float*  A0f  = (float*)(S);             // 0..64MB   (phase 1 only)
    ushort* BpT0 = (ushort*)(S);            // 0..16MB   (pool0)
    float*  h1   = (float*)(S);             // 0..2MB    (after BpT0 dead)
    ushort* BpT1 = (ushort*)(S + 2 * MB);   // 2..6MB
    float*  cA2f = (float*)(S + 6 * MB);    // 6..10MB
    float*  cA3f = (float*)(S + 10 * MB);   // 10..11MB
    float*  h2   = (float*)(S + 11 * MB);   // 11..12MB
    float*  cA1f = (float*)(S + 16 * MB);   // 16..32MB  (dead after convert)
    ushort* cA1h = (ushort*)(S + 32 * MB);  // 32..40MB
    float*  h0   = (float*)(S + 40 * MB);   // 40..44MB
    ushort* yT   = (ushort*)(S + 44 * MB);  // 44..48MB
    float*  xw   = (float*)(S + 48 * MB);   // 48..52MB
    float*  zbuf = (float*)(S + 52 * MB);   // 52..56MB
    float*  tA   = (float*)(S + 56 * MB);   // 56..60MB
    float*  tB   = (float*)(S + 60 * MB);   // 60..64MB
    ushort* A0h  = (ushort*)(S + 64 * MB);  // 64..96MB (live whole run)
    char* X = S + 96 * MB;
    auto xa = [&](size_t bytes) -> char* {
        char* p = X;
        X += (bytes + 255) & ~(size_t)255;
        return p;
    };
    float* dis   = (float*)xa(NN * 4);
    float* selfw = (float*)xa(NN * 4);
    float* score = (float*)xa(NN * 4);
    float* svals = (float*)xa(NN * 4);
    int*   rank  = (int*)xa(NN * 4);
    int*   sperm0 = (int*)xa(2048 * 4);
    int*   sperm1 = (int*)xa(1024 * 4);
    int*   sperm2 = (int*)xa(512 * 4);
    float* invn  = (float*)xa(256);
    float* meanb = (float*)xa(CC * 4);
    float* varb  = (float*)xa(CC * 4);

    // ---- 1. build fp32 adjacency, 2. convert to bf16 (exact small ints) ----
    k_zero<<<2048, 256, 0, stream>>>(A0f, (size_t)NN * NN);
    k_build_adj<<<EE / 256, 256, 0, stream>>>(ei, A0f);
    k_f2b<<<((size_t)NN * NN / 4 + 255) / 256, 256, 0, stream>>>(
        A0f, A0h, (size_t)NN * NN / 4);

    // ---- 3. down conv 0 (n=4096, MFMA) ----
    gcn_bf(A0h, NN, x, down_W, down_b, h0, 1, xw, zbuf, yT, dis, selfw, stream);

    // ---- 4-7. level 0 pooling: 4096 -> 2048 ----
    select_sorted(h0, pool_w, NN, 2048, invn, score, rank, sperm0, svals, stream);
    k_gate<<<2048, 256, 0, stream>>>(h0, sperm0, svals, tA);
    k_bpt<<<dim3(2048 / 64, NN / 64), 256, 0, stream>>>(A0h, sperm0, BpT0, NN);
    gemm_bf16<128><<<dim3(2048 / 128, 2048 / 128), 256, 0, stream>>>(
        A0h, sperm0, 0xFFFFFFFFu, 1, BpT0, cA1f,
        2048, 2048, NN, NN, NN, 2048, 1);
    // ---- 8. cA1 -> bf16 (entries < 256, exact) ----
    k_f2b<<<((size_t)2048 * 2048 / 4 + 255) / 256, 256, 0, stream>>>(
        cA1f, cA1h, (size_t)2048 * 2048 / 4);
    // ---- 9. down conv 1 (n=2048, MFMA) ----
    gcn_bf(cA1h, 2048, tA, down_W + 1 * CC * CC, down_b + 1 * CC, h1, 1,
           xw, zbuf, yT, dis, selfw, stream);

    // ---- 10-12. level 1 pooling: 2048 -> 1024 ----
    select_sorted(h1, pool_w + CC, 2048, 1024, invn, score, rank, sperm1, svals, stream);
    k_gate<<<1024, 256, 0, stream>>>(h1, sperm1, svals, tA);
    k_bpt<<<dim3(1024 / 64, 2048 / 64), 256, 0, stream>>>(cA1h, sperm1, BpT1, 2048);
    gemm_bf16<128><<<dim3(1024 / 128, 1024 / 128), 256, 0, stream>>>(
        cA1h, sperm1, 0xFFFFFFFFu, 1, BpT1, cA2f,
        1024, 1024, 2048, 2048, 2048, 1024, 1);
    // ---- 13. down conv 2 (n=1024, fp32) ----
    gcn_f32(cA2f, 1024, tA, down_W + 2 * CC * CC, down_b + 2 * CC, h2, 1,
            xw, zbuf, dis, selfw, stream);

    // ---- 14-16. level 2 pooling: 1024 -> 512, bottom conv ----
    select_sorted(h2, pool_w + 2 * CC, 1024, 512, invn, score, rank, sperm2, svals,
                  stream);
    k_gate<<<512, 256, 0, stream>>>(h2, sperm2, svals, tA);
    gemm_pool<<<dim3(512 / 64, 512 / 64), 256, 0, stream>>>(cA2f, sperm2, cA3f,
                                                            512, 1024);
    gcn_f32(cA3f, 512, tA, down_W + 3 * CC * CC, down_b + 3 * CC, tB, 1,
            xw, zbuf, dis, selfw, stream);

    // ---- 17. up i=0 (n=1024, fp32) ----
    hipMemcpyAsync(tA, h2, (size_t)1024 * CC * 4, hipMemcpyDeviceToDevice, stream);
    k_scatter_add<<<512, 256, 0, stream>>>(tA, tB, sperm2);
    gcn_f32(cA2f, 1024, tA, up_W, up_b, tB, 1, xw, zbuf, dis, selfw, stream);
    // ---- 18. up i=1 (n=2048, MFMA) ----
    hipMemcpyAsync(tA, h1, (size_t)2048 * CC * 4, hipMemcpyDeviceToDevice, stream);
    k_scatter_add<<<1024, 256, 0, stream>>>(tA, tB, sperm1);
    gcn_bf(cA1h, 2048, tA, up_W + 1 * CC * CC, up_b + 1 * CC, tB, 1,
           xw, zbuf, yT, dis, selfw, stream);
    // ---- 19. up i=2 (n=4096, MFMA, no relu) ----
    hipMemcpyAsync(tA, h0, (size_t)NN * CC * 4, hipMemcpyDeviceToDevice, stream);
    k_scatter_add<<<2048, 256, 0, stream>>>(tA, tB, sperm0);
    gcn_bf(A0h, NN, tA, up_W + 2 * CC * CC, up_b + 2 * CC, tB, 0,
           xw, zbuf, yT, dis, selfw, stream);

    // ---- 20. relu + batchnorm + linear ----
    k_bn_stats<<<CC, 256, 0, stream>>>(tB, meanb, varb, NN);
    k_bn_linear<<<NN, 256, 0, stream>>>(tB, meanb, varb, bn_g, bn_b, lin_W, lin_b, out);
}

// Round 9
// 1358.301 us; speedup vs baseline: 2.6534x; 1.4662x over previous
//
#include <hip/hip_runtime.h>
#include <cstdint>
#include <cstddef>

#define NN 4096
#define CC 256
#define EE 131072
#define OUTC 16
#define BN_EPS 1e-5f

typedef __attribute__((ext_vector_type(8))) short short8v;
typedef __attribute__((ext_vector_type(4))) float floatx4;

__device__ __forceinline__ float b2f(ushort u) {
    return __uint_as_float(((unsigned)u) << 16);
}
__device__ __forceinline__ ushort f2b(float f) {
    unsigned u = __float_as_uint(f);
    unsigned r = (u + 0x7FFFu + ((u >> 16) & 1u)) >> 16;
    return (ushort)r;
}

// ---------------------------------------------------------------- small kernels

__global__ __launch_bounds__(256) void k_zero(float* __restrict__ p, size_t n) {
    size_t i = (size_t)blockIdx.x * blockDim.x + threadIdx.x;
    size_t stride = (size_t)gridDim.x * blockDim.x;
    for (; i < n; i += stride) p[i] = 0.f;
}

__global__ __launch_bounds__(256) void k_build_adj(const int* __restrict__ ei,
                                                   float* __restrict__ A) {
    int e = blockIdx.x * blockDim.x + threadIdx.x;
    if (e < EE) {
        int s = ei[e];        // source
        int t = ei[EE + e];   // target
        atomicAdd(&A[(size_t)t * NN + s], 1.0f);
    }
}

// fp32 -> bf16 elementwise convert (count multiple of 4)
__global__ __launch_bounds__(256) void k_f2b(const float* __restrict__ in,
                                             ushort* __restrict__ out, size_t cnt4) {
    size_t i = (size_t)blockIdx.x * blockDim.x + threadIdx.x;
    if (i < cnt4) {
        float4 v = *reinterpret_cast<const float4*>(&in[i * 4]);
        ushort4 o;
        o.x = f2b(v.x); o.y = f2b(v.y); o.z = f2b(v.z); o.w = f2b(v.w);
        *reinterpret_cast<ushort4*>(&out[i * 4]) = o;
    }
}

// degree from fp32 adjacency
__global__ __launch_bounds__(256) void k_degree(const float* __restrict__ A,
                                                float* __restrict__ dis,
                                                float* __restrict__ selfw, int n) {
    int i = blockIdx.x;
    int tid = threadIdx.x;
    const float* row = A + (size_t)i * n;
    float s = 0.f;
    for (int j = tid; j < n; j += 256) s += row[j];
    __shared__ float ss[256];
    ss[tid] = s;
    __syncthreads();
    for (int off = 128; off > 0; off >>= 1) {
        if (tid < off) ss[tid] += ss[tid + off];
        __syncthreads();
    }
    if (tid == 0) {
        float d0 = row[i];
        float e = (d0 > 0.f) ? 0.f : 2.f;
        dis[i] = rsqrtf(ss[0] + e);
        selfw[i] = e;
    }
}

// degree from bf16 adjacency (vectorized short8 loads)
__global__ __launch_bounds__(256) void k_degree_bf(const ushort* __restrict__ Ah,
                                                   float* __restrict__ dis,
                                                   float* __restrict__ selfw, int n) {
    int i = blockIdx.x;
    int tid = threadIdx.x;
    const ushort* row = Ah + (size_t)i * n;
    float s = 0.f;
    int nc = n >> 3;
    for (int c = tid; c < nc; c += 256) {
        int4 v = *reinterpret_cast<const int4*>(row + c * 8);
        const ushort* u = (const ushort*)&v;
        #pragma unroll
        for (int m = 0; m < 8; ++m) s += b2f(u[m]);
    }
    __shared__ float ss[256];
    ss[tid] = s;
    __syncthreads();
    for (int off = 128; off > 0; off >>= 1) {
        if (tid < off) ss[tid] += ss[tid + off];
        __syncthreads();
    }
    if (tid == 0) {
        float d0 = b2f(row[i]);
        float e = (d0 > 0.f) ? 0.f : 2.f;
        dis[i] = rsqrtf(ss[0] + e);
        selfw[i] = e;
    }
}

// xw[i][c] *= dis[i]   (xw becomes y = dis ⊙ (x@W))
__global__ __launch_bounds__(256) void k_scale_rows(float* __restrict__ xw,
                                                    const float* __restrict__ dis) {
    int i = blockIdx.x, c = threadIdx.x;
    xw[(size_t)i * CC + c] *= dis[i];
}

// out = [relu]( dis_i * (z + selfw_i * y) + b )
__global__ __launch_bounds__(256) void k_gcn_epilogue(const float* __restrict__ z,
                                                      const float* __restrict__ y,
                                                      const float* __restrict__ dis,
                                                      const float* __restrict__ selfw,
                                                      const float* __restrict__ bias,
                                                      float* __restrict__ out,
                                                      int do_relu) {
    int i = blockIdx.x, c = threadIdx.x;
    float di = dis[i];
    float v = di * (z[(size_t)i * CC + c] + selfw[i] * y[(size_t)i * CC + c]) + bias[c];
    if (do_relu) v = fmaxf(v, 0.f);
    out[(size_t)i * CC + c] = v;
}

// split-K variant: z = sum over nslab partial slabs (stride n*CC)
__global__ __launch_bounds__(256) void k_gcn_epilogue_s(const float* __restrict__ zpart,
                                                        int nslab, int n,
                                                        const float* __restrict__ y,
                                                        const float* __restrict__ dis,
                                                        const float* __restrict__ selfw,
                                                        const float* __restrict__ bias,
                                                        float* __restrict__ out,
                                                        int do_relu) {
    int i = blockIdx.x, c = threadIdx.x;
    size_t idx = (size_t)i * CC + c;
    size_t stride = (size_t)n * CC;
    float z = 0.f;
    for (int s = 0; s < nslab; ++s) z += zpart[(size_t)s * stride + idx];
    float di = dis[i];
    float v = di * (z + selfw[i] * y[idx]) + bias[c];
    if (do_relu) v = fmaxf(v, 0.f);
    out[idx] = v;
}

__global__ __launch_bounds__(256) void k_wnorm(const float* __restrict__ w,
                                               float* __restrict__ invn) {
    __shared__ float ss[256];
    int tid = threadIdx.x;
    float v = w[tid];
    ss[tid] = v * v;
    __syncthreads();
    for (int off = 128; off > 0; off >>= 1) {
        if (tid < off) ss[tid] += ss[tid + off];
        __syncthreads();
    }
    if (tid == 0) invn[0] = rsqrtf(ss[0]);
}

__global__ __launch_bounds__(256) void k_score(const float* __restrict__ h,
                                               const float* __restrict__ w,
                                               const float* __restrict__ invn,
                                               float* __restrict__ score) {
    int i = blockIdx.x, tid = threadIdx.x;
    __shared__ float ss[256];
    ss[tid] = h[(size_t)i * CC + tid] * w[tid];
    __syncthreads();
    for (int off = 128; off > 0; off >>= 1) {
        if (tid < off) ss[tid] += ss[tid + off];
        __syncthreads();
    }
    if (tid == 0) score[i] = tanhf(ss[0] * invn[0]);
}

// rank[i] = #{s_j > s_i} + #{s_j==s_i, j<i}  (PyG topk tie-break)
__global__ __launch_bounds__(256) void k_rank(const float* __restrict__ score, int n,
                                              int* __restrict__ rank) {
    extern __shared__ float sc[];
    int tid = threadIdx.x;
    for (int j = tid; j < n; j += 256) sc[j] = score[j];
    __syncthreads();
    int i = blockIdx.x * 256 + tid;
    if (i < n) {
        float s = sc[i];
        int rk = 0;
        for (int j = 0; j < n; ++j) {
            float sj = sc[j];
            rk += (sj > s) || (sj == s && j < i);
        }
        rank[i] = rk;
    }
}

// selected nodes (rank<k) compacted in ASCENDING INDEX order
__global__ __launch_bounds__(256) void k_sortsel(const float* __restrict__ score,
                                                 const int* __restrict__ rank,
                                                 int n, int k, int* __restrict__ sperm,
                                                 float* __restrict__ svals) {
    extern __shared__ int sr[];
    int tid = threadIdx.x;
    for (int j = tid; j < n; j += 256) sr[j] = (rank[j] < k) ? 1 : 0;
    __syncthreads();
    int i = blockIdx.x * 256 + tid;
    if (i < n && sr[i]) {
        int pos = 0;
        for (int j = 0; j < i; ++j) pos += sr[j];
        sperm[pos] = i;
        svals[pos] = score[i];
    }
}

// out[a][c] = h[sperm[a]][c] * svals[a]
__global__ __launch_bounds__(256) void k_gate(const float* __restrict__ h,
                                              const int* __restrict__ perm,
                                              const float* __restrict__ vals,
                                              float* __restrict__ out) {
    int a = blockIdx.x, c = threadIdx.x;
    out[(size_t)a * CC + c] = h[(size_t)perm[a] * CC + c] * vals[a];
}

__global__ __launch_bounds__(256) void k_scatter_add(float* __restrict__ dst,
                                                     const float* __restrict__ src,
                                                     const int* __restrict__ perm) {
    int a = blockIdx.x, c = threadIdx.x;
    dst[(size_t)perm[a] * CC + c] += src[(size_t)a * CC + c];
}

__global__ __launch_bounds__(256) void k_bn_stats(const float* __restrict__ h,
                                                  float* __restrict__ mean,
                                                  float* __restrict__ var, int n) {
    int c = blockIdx.x, tid = threadIdx.x;
    float s = 0.f, s2 = 0.f;
    for (int r = tid; r < n; r += 256) {
        float v = fmaxf(h[(size_t)r * CC + c], 0.f);
        s += v;
        s2 += v * v;
    }
    __shared__ float ss[256], ss2[256];
    ss[tid] = s;
    ss2[tid] = s2;
    __syncthreads();
    for (int off = 128; off > 0; off >>= 1) {
        if (tid < off) { ss[tid] += ss[tid + off]; ss2[tid] += ss2[tid + off]; }
        __syncthreads();
    }
    if (tid == 0) {
        float m = ss[0] / n;
        mean[c] = m;
        var[c] = ss2[0] / n - m * m;
    }
}

__global__ __launch_bounds__(256) void k_bn_linear(const float* __restrict__ h,
                                                   const float* __restrict__ mean,
                                                   const float* __restrict__ var,
                                                   const float* __restrict__ gamma,
                                                   const float* __restrict__ beta,
                                                   const float* __restrict__ W,
                                                   const float* __restrict__ b,
                                                   float* __restrict__ out) {
    int i = blockIdx.x, tid = threadIdx.x;
    __shared__ float t[CC];
    float v = fmaxf(h[(size_t)i * CC + tid], 0.f);
    t[tid] = (v - mean[tid]) * rsqrtf(var[tid] + BN_EPS) * gamma[tid] + beta[tid];
    __syncthreads();
    if (tid < OUTC) {
        float acc = b[tid];
        #pragma unroll 8
        for (int c = 0; c < CC; ++c) acc += t[c] * W[c * OUTC + tid];
        out[(size_t)i * OUTC + tid] = acc;
    }
}

// y (n x 256 fp32) -> yT (256 x 2n bf16): cols [0,n)=hi split, [n,2n)=lo split
__global__ __launch_bounds__(256) void k_ysplit(const float* __restrict__ y,
                                                ushort* __restrict__ yT, int n) {
    __shared__ float L[64][65];
    int t = threadIdx.x;
    int i0 = blockIdx.x * 64, c0 = blockIdx.y * 64;
    #pragma unroll
    for (int e = 0; e < 16; ++e) {
        int idx = e * 256 + t;
        int c = idx & 63, r = idx >> 6;
        L[r][c] = y[(size_t)(i0 + r) * CC + c0 + c];
    }
    __syncthreads();
    #pragma unroll
    for (int e = 0; e < 16; ++e) {
        int idx = e * 256 + t;
        int ii = idx & 63, cc = idx >> 6;
        float v = L[ii][cc];
        ushort hi = f2b(v);
        float lo = v - b2f(hi);
        size_t base = (size_t)(c0 + cc) * (size_t)(2 * n) + i0 + ii;
        yT[base] = hi;
        yT[base + n] = f2b(lo);
    }
}

// BpT[b][j] = (j==ps[b]) ? 1 : Ah[j][ps[b]]   (gather-transpose with A1 diag)
__global__ __launch_bounds__(256) void k_bpt(const ushort* __restrict__ Ah,
                                             const int* __restrict__ ps,
                                             ushort* __restrict__ BpT, int n) {
    __shared__ ushort L[64][65];
    __shared__ int pcols[64];
    int t = threadIdx.x;
    int b0 = blockIdx.x * 64, j0 = blockIdx.y * 64;
    if (t < 64) pcols[t] = ps[b0 + t];
    __syncthreads();
    #pragma unroll
    for (int e = 0; e < 16; ++e) {
        int idx = e * 256 + t;
        int c = idx & 63, r = idx >> 6;
        L[r][c] = Ah[(size_t)(j0 + r) * n + pcols[c]];
    }
    __syncthreads();
    #pragma unroll
    for (int e = 0; e < 16; ++e) {
        int idx = e * 256 + t;
        int jj = idx & 63, bb = idx >> 6;
        ushort v = L[jj][bb];
        if (j0 + jj == pcols[bb]) v = 0x3F80;   // bf16(1.0)
        BpT[(size_t)(b0 + bb) * n + j0 + jj] = v;
    }
}

// ---------------------------------------------------------------- bf16 MFMA GEMM
// C[M][N] = A'[M][K] @ B[K][N] with BT (N x K row-major) given.
// A'[i][k] = A[permA?permA[i]:i][k & kmask], optionally patched A1-diag (k==pa -> 1).
// 4 waves (2x2), BK=32, 16x16x32 bf16 MFMA, reg-staged LDS (pad 40).
// Split-K: blockIdx.z covers K/ksplit contiguous slab; f32 partials go to
// C + z*M*N (reduce elsewhere). When Cbf != null (requires ksplit==1), the
// output is written bf16 directly (exact for small-int results).
template<int BM, int BN>
__global__ __launch_bounds__(256) void gemm_bf16(
    const ushort* __restrict__ A, const int* __restrict__ permA, unsigned kmask,
    int diagA, const ushort* __restrict__ BT, float* __restrict__ C,
    ushort* __restrict__ Cbf,
    int M, int N, int K, int lda, int ldbt, int ldc, int zero_diag, int ksplit)
{
    constexpr int BK = 32;
    constexpr int WM = BM / 2;
    constexpr int WN = BN / 2;
    constexpr int FM = WM / 16;
    constexpr int FN = WN / 16;
    constexpr int AP = BM / 64;        // A staging passes
    constexpr int BP = BN / 64;        // B staging passes
    __shared__ ushort As[BM][40];
    __shared__ ushort Bs[BN][40];
    const int tid = threadIdx.x;
    const int lane = tid & 63;
    const int w = tid >> 6;
    const int wr = w >> 1, wc = w & 1;
    const int bm = blockIdx.x * BM, bn = blockIdx.y * BN;
    const int srow = tid >> 2;         // 0..63
    const int schk = tid & 3;          // 16B chunk within 64B row

    const int kslab = K / ksplit;
    const int kbeg = blockIdx.z * kslab;
    const int kend = kbeg + kslab;

    int arow[AP];
    const ushort* aptr[AP];
    #pragma unroll
    for (int p = 0; p < AP; ++p) {
        int gr = bm + srow + p * 64;
        int pa = permA ? permA[gr] : gr;
        arow[p] = pa;
        aptr[p] = A + (size_t)pa * lda;
    }
    const ushort* bptr[BP];
    #pragma unroll
    for (int p = 0; p < BP; ++p)
        bptr[p] = BT + (size_t)(bn + srow + p * 64) * ldbt;

    floatx4 acc[FM][FN];
    #pragma unroll
    for (int i = 0; i < FM; ++i)
        #pragma unroll
        for (int j = 0; j < FN; ++j) {
            floatx4 z4 = {0.f, 0.f, 0.f, 0.f};
            acc[i][j] = z4;
        }

    int4 ra[AP], rb[BP];
    // preload first K-step of this slab
    {
        const int jb = kbeg + schk * 8;
        const int jm = (int)((unsigned)jb & kmask);
        #pragma unroll
        for (int p = 0; p < AP; ++p) {
            ra[p] = *reinterpret_cast<const int4*>(aptr[p] + jm);
            if (diagA) {
                int d = arow[p] - jm;
                if (d >= 0 && d < 8) ((ushort*)&ra[p])[d] = 0x3F80;
            }
        }
        #pragma unroll
        for (int p = 0; p < BP; ++p)
            rb[p] = *reinterpret_cast<const int4*>(bptr[p] + jb);
    }

    for (int k0 = kbeg; k0 < kend; k0 += BK) {
        __syncthreads();
        #pragma unroll
        for (int p = 0; p < AP; ++p)
            *reinterpret_cast<int4*>(&As[srow + p * 64][schk * 8]) = ra[p];
        #pragma unroll
        for (int p = 0; p < BP; ++p)
            *reinterpret_cast<int4*>(&Bs[srow + p * 64][schk * 8]) = rb[p];
        __syncthreads();
        if (k0 + BK < kend) {
            const int jb = k0 + BK + schk * 8;
            const int jm = (int)((unsigned)jb & kmask);
            #pragma unroll
            for (int p = 0; p < AP; ++p) {
                ra[p] = *reinterpret_cast<const int4*>(aptr[p] + jm);
                if (diagA) {
                    int d = arow[p] - jm;
                    if (d >= 0 && d < 8) ((ushort*)&ra[p])[d] = 0x3F80;
                }
            }
            #pragma unroll
            for (int p = 0; p < BP; ++p)
                rb[p] = *reinterpret_cast<const int4*>(bptr[p] + jb);
        }
        const int k8 = (lane >> 4) * 8;
        const int l15 = lane & 15;
        short8v a[FM], b[FN];
        #pragma unroll
        for (int j = 0; j < FN; ++j)
            b[j] = *reinterpret_cast<const short8v*>(&Bs[wc * WN + j * 16 + l15][k8]);
        #pragma unroll
        for (int i = 0; i < FM; ++i)
            a[i] = *reinterpret_cast<const short8v*>(&As[wr * WM + i * 16 + l15][k8]);
        #pragma unroll
        for (int i = 0; i < FM; ++i)
            #pragma unroll
            for (int j = 0; j < FN; ++j)
                acc[i][j] = __builtin_amdgcn_mfma_f32_16x16x32_bf16(
                    a[i], b[j], acc[i][j], 0, 0, 0);
    }

    // epilogue: C/D layout col=lane&15, row=(lane>>4)*4+reg
    float* Cout = C + (size_t)blockIdx.z * (size_t)M * (size_t)N;
    #pragma unroll
    for (int i = 0; i < FM; ++i) {
        #pragma unroll
        for (int j = 0; j < FN; ++j) {
            int gcol = bn + wc * WN + j * 16 + (lane & 15);
            #pragma unroll
            for (int r = 0; r < 4; ++r) {
                int grow = bm + wr * WM + i * 16 + (lane >> 4) * 4 + r;
                float v = acc[i][j][r];
                if (zero_diag && grow == gcol) v = 0.f;
                if (Cbf) Cbf[(size_t)grow * ldc + gcol] = f2b(v);
                else Cout[(size_t)grow * ldc + gcol] = v;
            }
        }
    }
}

// ---------------------------------------------------------------- fp32 GEMM (small)
__global__ __launch_bounds__(256) void gemm_f32(const float* __restrict__ A,
                                                const float* __restrict__ B,
                                                float* __restrict__ C,
                                                int M, int N, int K,
                                                int lda, int ldb, int ldc) {
    __shared__ float As[16][72];
    __shared__ float Bs[16][72];
    const int tid = threadIdx.x;
    const int bm = blockIdx.x * 64;
    const int bn = blockIdx.y * 64;
    const int tx = tid & 15, ty = tid >> 4;
    const int ar = tid >> 2;
    const int ak = (tid & 3) << 2;
    const int bk = tid >> 4;
    const int bc = (tid & 15) << 2;
    float acc[4][4] = {};
    for (int k0 = 0; k0 < K; k0 += 16) {
        const float4 av = *reinterpret_cast<const float4*>(
            &A[(size_t)(bm + ar) * lda + k0 + ak]);
        const float4 bv = *reinterpret_cast<const float4*>(
            &B[(size_t)(k0 + bk) * ldb + bn + bc]);
        __syncthreads();
        As[ak + 0][ar] = av.x;
        As[ak + 1][ar] = av.y;
        As[ak + 2][ar] = av.z;
        As[ak + 3][ar] = av.w;
        *reinterpret_cast<float4*>(&Bs[bk][bc]) = bv;
        __syncthreads();
        #pragma unroll
        for (int kk = 0; kk < 16; ++kk) {
            float4 a = *reinterpret_cast<const float4*>(&As[kk][ty << 2]);
            float4 b = *reinterpret_cast<const float4*>(&Bs[kk][tx << 2]);
            acc[0][0] += a.x * b.x; acc[0][1] += a.x * b.y;
            acc[0][2] += a.x * b.z; acc[0][3] += a.x * b.w;
            acc[1][0] += a.y * b.x; acc[1][1] += a.y * b.y;
            acc[1][2] += a.y * b.z; acc[1][3] += a.y * b.w;
            acc[2][0] += a.z * b.x; acc[2][1] += a.z * b.y;
            acc[2][2] += a.z * b.z; acc[2][3] += a.z * b.w;
            acc[3][0] += a.w * b.x; acc[3][1] += a.w * b.y;
            acc[3][2] += a.w * b.z; acc[3][3] += a.w * b.w;
        }
    }
    #pragma unroll
    for (int i = 0; i < 4; ++i) {
        float4 v = make_float4(acc[i][0], acc[i][1], acc[i][2], acc[i][3]);
        *reinterpret_cast<float4*>(
            &C[(size_t)(bm + (ty << 2) + i) * ldc + bn + (tx << 2)]) = v;
    }
}

// fused fp32 pooling GEMM (level-2 only; sorted perm -> decent locality)
__global__ __launch_bounds__(256) void gemm_pool(const float* __restrict__ A,
                                                 const int* __restrict__ perm,
                                                 float* __restrict__ C,
                                                 int k, int n) {
    __shared__ float As[16][72];
    __shared__ float Bs[16][72];
    const int tid = threadIdx.x;
    const int bm = blockIdx.x * 64;
    const int bn = blockIdx.y * 64;
    const int tx = tid & 15, ty = tid >> 4;
    const int ar = tid >> 2;
    const int ak = (tid & 3) << 2;
    const int bk = tid >> 4;
    const int bc = (tid & 15) << 2;
    const int pa  = perm[bm + ar];
    const int pc0 = perm[bn + bc + 0];
    const int pc1 = perm[bn + bc + 1];
    const int pc2 = perm[bn + bc + 2];
    const int pc3 = perm[bn + bc + 3];
    float acc[4][4] = {};
    for (int k0 = 0; k0 < n; k0 += 16) {
        float4 av = *reinterpret_cast<const float4*>(&A[(size_t)pa * n + k0 + ak]);
        if (k0 + ak + 0 == pa) av.x = 1.f;
        if (k0 + ak + 1 == pa) av.y = 1.f;
        if (k0 + ak + 2 == pa) av.z = 1.f;
        if (k0 + ak + 3 == pa) av.w = 1.f;
        const int jrow = k0 + bk;
        const size_t jb = (size_t)jrow * n;
        float b0 = (jrow == pc0) ? 1.f : A[jb + pc0];
        float b1 = (jrow == pc1) ? 1.f : A[jb + pc1];
        float b2 = (jrow == pc2) ? 1.f : A[jb + pc2];
        float b3 = (jrow == pc3) ? 1.f : A[jb + pc3];
        __syncthreads();
        As[ak + 0][ar] = av.x;
        As[ak + 1][ar] = av.y;
        As[ak + 2][ar] = av.z;
        As[ak + 3][ar] = av.w;
        Bs[bk][bc + 0] = b0;
        Bs[bk][bc + 1] = b1;
        Bs[bk][bc + 2] = b2;
        Bs[bk][bc + 3] = b3;
        __syncthreads();
        #pragma unroll
        for (int kk = 0; kk < 16; ++kk) {
            float4 a = *reinterpret_cast<const float4*>(&As[kk][ty << 2]);
            float4 b = *reinterpret_cast<const float4*>(&Bs[kk][tx << 2]);
            acc[0][0] += a.x * b.x; acc[0][1] += a.x * b.y;
            acc[0][2] += a.x * b.z; acc[0][3] += a.x * b.w;
            acc[1][0] += a.y * b.x; acc[1][1] += a.y * b.y;
            acc[1][2] += a.y * b.z; acc[1][3] += a.y * b.w;
            acc[2][0] += a.z * b.x; acc[2][1] += a.z * b.y;
            acc[2][2] += a.z * b.z; acc[2][3] += a.z * b.w;
            acc[3][0] += a.w * b.x; acc[3][1] += a.w * b.y;
            acc[3][2] += a.w * b.z; acc[3][3] += a.w * b.w;
        }
    }
    #pragma unroll
    for (int i = 0; i < 4; ++i) {
        const int ga = bm + (ty << 2) + i;
        const int gb = bn + (tx << 2);
        float4 v;
        v.x = (ga == gb + 0) ? 0.f : acc[i][0];
        v.y = (ga == gb + 1) ? 0.f : acc[i][1];
        v.z = (ga == gb + 2) ? 0.f : acc[i][2];
        v.w = (ga == gb + 3) ? 0.f : acc[i][3];
        *reinterpret_cast<float4*>(&C[(size_t)ga * k + gb]) = v;
    }
}

// ---------------------------------------------------------------- host-side helpers

#define KSPLIT 8

// GCN with bf16-MFMA aggregation: z = Ah @ (yh + yl), K = 2n trick, split-K
static void gcn_bf(const ushort* Ah, int n, const float* xin, const float* W,
                   const float* bias, float* outp, int relu,
                   float* xw, float* zpart, ushort* yT, float* dis, float* selfw,
                   hipStream_t s) {
    k_degree_bf<<<n, 256, 0, s>>>(Ah, dis, selfw, n);
    gemm_f32<<<dim3(n / 64, 4), 256, 0, s>>>(xin, W, xw, n, CC, CC, CC, CC, CC);
    k_scale_rows<<<n, 256, 0, s>>>(xw, dis);
    k_ysplit<<<dim3(n / 64, 4), 256, 0, s>>>(xw, yT, n);
    gemm_bf16<64, 128><<<dim3(n / 64, CC / 128, KSPLIT), 256, 0, s>>>(
        Ah, nullptr, (unsigned)(n - 1), 0, yT, zpart, nullptr,
        n, CC, 2 * n, n, 2 * n, CC, 0, KSPLIT);
    k_gcn_epilogue_s<<<n, 256, 0, s>>>(zpart, KSPLIT, n, xw, dis, selfw, bias,
                                       outp, relu);
}

// fp32 GCN (small levels)
static void gcn_f32(const float* A, int n, const float* xin, const float* W,
                    const float* bias, float* outp, int relu,
                    float* xw, float* zbuf, float* dis, float* selfw,
                    hipStream_t s) {
    k_degree<<<n, 256, 0, s>>>(A, dis, selfw, n);
    gemm_f32<<<dim3(n / 64, 4), 256, 0, s>>>(xin, W, xw, n, CC, CC, CC, CC, CC);
    k_scale_rows<<<n, 256, 0, s>>>(xw, dis);
    gemm_f32<<<dim3(n / 64, 4), 256, 0, s>>>(A, xw, zbuf, n, CC, n, n, CC, CC);
    k_gcn_epilogue<<<n, 256, 0, s>>>(zbuf, xw, dis, selfw, bias, outp, relu);
}

// scoring + sorted top-k selection
static void select_sorted(const float* h, const float* pw, int n, int k,
                          float* invn, float* score, int* rank,
                          int* sperm, float* svals, hipStream_t s) {
    k_wnorm<<<1, 256, 0, s>>>(pw, invn);
    k_score<<<n, 256, 0, s>>>(h, pw, invn, score);
    k_rank<<<(n + 255) / 256, 256, n * 4, s>>>(score, n, rank);
    k_sortsel<<<(n + 255) / 256, 256, n * 4, s>>>(score, rank, n, k, sperm, svals);
}

extern "C" void kernel_launch(void* const* d_in, const int* in_sizes, int n_in,
                              void* d_out, int out_size, void* d_ws, size_t ws_size,
                              hipStream_t stream) {
    const float* x       = (const float*)d_in[0];
    const int*   ei      = (const int*)d_in[1];
    const float* down_W  = (const float*)d_in[2];
    const float* down_b  = (const float*)d_in[3];
    const float* pool_w  = (const float*)d_in[4];
    const float* up_W    = (const float*)d_in[5];
    const float* up_b    = (const float*)d_in[6];
    const float* bn_g    = (const float*)d_in[7];
    const float* bn_b    = (const float*)d_in[8];
    const float* lin_W   = (const float*)d_in[9];
    const float* lin_b   = (const float*)d_in[10];
    float* out = (float*)d_out;
    (void)ws_size; (void)n_in; (void)in_sizes; (void)out_size;

    // ---- workspace layout (lifetime-overlaid), peak 108 MB (= R2-proven) ----
    const size_t MB = 1ull << 20;
    char* S = (char*)d_ws;
    float*  A0f  = (float*)(S);             // 0..64MB   (phase 1 only)
    ushort* BpT0 = (ushort*)(S);            // 0..16MB   (pool0 B-transpose)
    float*  h1   = (float*)(S);             // 0..2MB    (after BpT0 dead)
    ushort* BpT1 = (ushort*)(S + 2 * MB);   // 2..6MB
    float*  cA2f = (float*)(S + 6 * MB);    // 6..10MB
    float*  cA3f = (float*)(S + 10 * MB);   // 10..11MB
    float*  h2   = (float*)(S + 11 * MB);   // 11..12MB
    float*  zpart= (float*)(S + 16 * MB);   // 16..48MB  (split-K partials, 32 MB)
    float*  h0   = (float*)(S + 48 * MB);   // 48..52MB
    ushort* yT   = (ushort*)(S + 52 * MB);  // 52..56MB
    float*  xw   = (float*)(S + 56 * MB);   // 56..60MB
    float*  tA   = (float*)(S + 60 * MB);   // 60..64MB
    float*  tB   = (float*)(S + 64 * MB);   // 64..68MB
    ushort* cA1h = (ushort*)(S + 68 * MB);  // 68..76MB
    ushort* A0h  = (ushort*)(S + 76 * MB);  // 76..108MB (live whole run)
    char* X = S + 108 * MB;
    auto xa = [&](size_t bytes) -> char* {
        char* p = X;
        X += (bytes + 255) & ~(size_t)255;
        return p;
    };
    float* dis   = (float*)xa(NN * 4);
    float* selfw = (float*)xa(NN * 4);
    float* score = (float*)xa(NN * 4);
    float* svals = (float*)xa(NN * 4);
    int*   rank  = (int*)xa(NN * 4);
    int*   sperm0 = (int*)xa(2048 * 4);
    int*   sperm1 = (int*)xa(1024 * 4);
    int*   sperm2 = (int*)xa(512 * 4);
    float* invn  = (float*)xa(256);
    float* meanb = (float*)xa(CC * 4);
    float* varb  = (float*)xa(CC * 4);

    // ---- 1. build fp32 adjacency, 2. convert to bf16 (exact small ints) ----
    k_zero<<<2048, 256, 0, stream>>>(A0f, (size_t)NN * NN);
    k_build_adj<<<EE / 256, 256, 0, stream>>>(ei, A0f);
    k_f2b<<<((size_t)NN * NN / 4 + 255) / 256, 256, 0, stream>>>(
        A0f, A0h, (size_t)NN * NN / 4);

    // ---- 3. down conv 0 (n=4096, MFMA split-K) ----
    gcn_bf(A0h, NN, x, down_W, down_b, h0, 1, xw, zpart, yT, dis, selfw, stream);

    // ---- 4-7. level 0 pooling: 4096 -> 2048 (64x64 tiles, bf16 direct out) ----
    select_sorted(h0, pool_w, NN, 2048, invn, score, rank, sperm0, svals, stream);
    k_gate<<<2048, 256, 0, stream>>>(h0, sperm0, svals, tA);
    k_bpt<<<dim3(2048 / 64, NN / 64), 256, 0, stream>>>(A0h, sperm0, BpT0, NN);
    gemm_bf16<64, 64><<<dim3(2048 / 64, 2048 / 64, 1), 256, 0, stream>>>(
        A0h, sperm0, 0xFFFFFFFFu, 1, BpT0, nullptr, cA1h,
        2048, 2048, NN, NN, NN, 2048, 1, 1);
    // ---- 8. down conv 1 (n=2048, MFMA split-K) ----
    gcn_bf(cA1h, 2048, tA, down_W + 1 * CC * CC, down_b + 1 * CC, h1, 1,
           xw, zpart, yT, dis, selfw, stream);

    // ---- 9-11. level 1 pooling: 2048 -> 1024 (64x64 tiles, f32 direct out) ----
    select_sorted(h1, pool_w + CC, 2048, 1024, invn, score, rank, sperm1, svals, stream);
    k_gate<<<1024, 256, 0, stream>>>(h1, sperm1, svals, tA);
    k_bpt<<<dim3(1024 / 64, 2048 / 64), 256, 0, stream>>>(cA1h, sperm1, BpT1, 2048);
    gemm_bf16<64, 64><<<dim3(1024 / 64, 1024 / 64, 1), 256, 0, stream>>>(
        cA1h, sperm1, 0xFFFFFFFFu, 1, BpT1, cA2f, nullptr,
        1024, 1024, 2048, 2048, 2048, 1024, 1, 1);
    // ---- 12. down conv 2 (n=1024, fp32) ----
    gcn_f32(cA2f, 1024, tA, down_W + 2 * CC * CC, down_b + 2 * CC, h2, 1,
            xw, zpart, dis, selfw, stream);

    // ---- 13-15. level 2 pooling: 1024 -> 512, bottom conv ----
    select_sorted(h2, pool_w + 2 * CC, 1024, 512, invn, score, rank, sperm2, svals,
                  stream);
    k_gate<<<512, 256, 0, stream>>>(h2, sperm2, svals, tA);
    gemm_pool<<<dim3(512 / 64, 512 / 64), 256, 0, stream>>>(cA2f, sperm2, cA3f,
                                                            512, 1024);
    gcn_f32(cA3f, 512, tA, down_W + 3 * CC * CC, down_b + 3 * CC, tB, 1,
            xw, zpart, dis, selfw, stream);

    // ---- 16. up i=0 (n=1024, fp32) ----
    hipMemcpyAsync(tA, h2, (size_t)1024 * CC * 4, hipMemcpyDeviceToDevice, stream);
    k_scatter_add<<<512, 256, 0, stream>>>(tA, tB, sperm2);
    gcn_f32(cA2f, 1024, tA, up_W, up_b, tB, 1, xw, zpart, dis, selfw, stream);
    // ---- 17. up i=1 (n=2048, MFMA split-K) ----
    hipMemcpyAsync(tA, h1, (size_t)2048 * CC * 4, hipMemcpyDeviceToDevice, stream);
    k_scatter_add<<<1024, 256, 0, stream>>>(tA, tB, sperm1);
    gcn_bf(cA1h, 2048, tA, up_W + 1 * CC * CC, up_b + 1 * CC, tB, 1,
           xw, zpart, yT, dis, selfw, stream);
    // ---- 18. up i=2 (n=4096, MFMA split-K, no relu) ----
    hipMemcpyAsync(tA, h0, (size_t)NN * CC * 4, hipMemcpyDeviceToDevice, stream);
    k_scatter_add<<<2048, 256, 0, stream>>>(tA, tB, sperm0);
    gcn_bf(A0h, NN, tA, up_W + 2 * CC * CC, up_b + 2 * CC, tB, 0,
           xw, zpart, yT, dis, selfw, stream);

    // ---- 19. relu + batchnorm + linear ----
    k_bn_stats<<<CC, 256, 0, stream>>>(tB, meanb, varb, NN);
    k_bn_linear<<<NN, 256, 0, stream>>>(tB, meanb, varb, bn_g, bn_b, lin_W, lin_b, out);
}